// Round 4
// baseline (2904.027 us; speedup 1.0000x reference)
//
#include <hip/hip_runtime.h>
#include <hip/hip_bf16.h>

#define DD 256   // feature dim
#define NM 64    // memory slots

typedef unsigned int u32;
typedef unsigned long long u64;

// ---------------------------------------------------------------------------
// prep: kT[o][n] = k[n][o] = sum_d mem[n][d]*Wk[o][d]  (fp32, d-ascending FMA
//       -- mimics sgemm single-accumulator semantics)
//       bias[n] = fl32(max(log(imp*0.99^age), -10))
// ---------------------------------------------------------------------------
__global__ __launch_bounds__(256) void prep_kT(
    const float* __restrict__ mem,   // [NM][DD]
    const float* __restrict__ Wk,    // [DD][DD]
    const float* __restrict__ imp,   // [NM]
    const float* __restrict__ age,   // [NM]
    float* __restrict__ kT,          // out [DD][NM]
    float* __restrict__ bias)        // out [NM]
{
    const int n = blockIdx.x;   // memory slot
    const int o = threadIdx.x;  // output feature
    const float* mrow = mem + n * DD;
    const float* wrow = Wk + o * DD;
    float acc = 0.f;
    for (int d = 0; d < DD; ++d)
        acc = fmaf(mrow[d], wrow[d], acc);
    kT[o * NM + n] = acc;

    if (o == 0) {
        // fp64-computed, rounded to fp32: matches correctly-rounded libm
        double eff = (double)imp[n] * pow(0.99, (double)age[n]);
        float b = (float)log(eff);
        if (!(b >= -10.0f)) b = -10.0f;   // catches -inf/NaN too
        bias[n] = b;
    }
}

// ---------------------------------------------------------------------------
// mb_main: one query row per lane. Full fp32 pipeline mimicking numpy:
//   q[o] = sum_d query[d]*Wq[o][d]     (fp32 FMA, d-ascending)
//   s[n] = sum_o q[o]*k[n][o]          (fp32 FMA, o-ascending)
//   s = s/16 + bias; top-k (strict >, lowest index ties); softmax fp32.
// ---------------------------------------------------------------------------
__global__ __launch_bounds__(64, 1) void mb_main(
    const float* __restrict__ query,   // [M][DD]
    const float* __restrict__ mem,     // [NM][DD]
    const float* __restrict__ Wq,      // [DD][DD]
    const float* __restrict__ kT,      // [DD][NM]
    const float* __restrict__ bias,    // [NM]
    const int* __restrict__ topk_p,
    float* __restrict__ out_ret,       // [M][DD] fp32
    float* __restrict__ out_attn,      // [M][NM] fp32
    int M)
{
    __shared__ int   sel_idx[16 * 64];
    __shared__ float sel_w[16 * 64];

    const int lane = threadIdx.x;
    const int row  = blockIdx.x * 64 + lane;
    if (row >= M) return;
    const float* qrow = query + (size_t)row * DD;

    // query row into registers
    float qr[DD];
    const float4* q4 = reinterpret_cast<const float4*>(qrow);
#pragma unroll
    for (int i = 0; i < DD / 4; ++i) {
        const float4 v = q4[i];
        qr[4 * i]     = v.x;
        qr[4 * i + 1] = v.y;
        qr[4 * i + 2] = v.z;
        qr[4 * i + 3] = v.w;
    }

    float s[NM];
#pragma unroll
    for (int n = 0; n < NM; ++n) s[n] = 0.f;

    // ---- q (4 output features at a time) + score accumulation, o-ascending
    for (int oc = 0; oc < DD / 4; ++oc) {
        const float* w0 = Wq + (size_t)(4 * oc) * DD;   // wave-uniform
        float qv0 = 0.f, qv1 = 0.f, qv2 = 0.f, qv3 = 0.f;
#pragma unroll
        for (int d = 0; d < DD; ++d) {
            const float qd = qr[d];
            qv0 = fmaf(qd, w0[d], qv0);
            qv1 = fmaf(qd, w0[DD + d], qv1);
            qv2 = fmaf(qd, w0[2 * DD + d], qv2);
            qv3 = fmaf(qd, w0[3 * DD + d], qv3);
        }
        const float* kt = kT + (size_t)(4 * oc) * NM;   // wave-uniform
#pragma unroll
        for (int n = 0; n < NM; ++n) {
            float sn = s[n];
            sn = fmaf(qv0, kt[n], sn);
            sn = fmaf(qv1, kt[NM + n], sn);
            sn = fmaf(qv2, kt[2 * NM + n], sn);
            sn = fmaf(qv3, kt[3 * NM + n], sn);
            s[n] = sn;
        }
    }

    // scale (exact: /16) + bias (fp32 add)
#pragma unroll
    for (int n = 0; n < NM; ++n)
        s[n] = s[n] * 0.0625f + bias[n];

    const int k = *topk_p;
    u64 taken = 0ull;
    float mmax = 0.f;
    float Z = 0.f;

    if (k < NM) {
        const int kk = k < 16 ? k : 16;    // dataset: k = 8
        for (int i = 0; i < kk; ++i) {
            float m = -1.0e30f;
            int idx = 0;
#pragma unroll
            for (int n = 0; n < NM; ++n) {
                const bool avail  = ((taken >> n) & 1ull) == 0ull;
                const bool better = avail && (s[n] > m);  // strict >: lowest idx ties
                m   = better ? s[n] : m;
                idx = better ? n : idx;
            }
            taken |= (1ull << idx);
            if (i == 0) mmax = m;
            const float w = expf(m - mmax);
            Z += w;
            sel_idx[i * 64 + lane] = idx;
            sel_w[i * 64 + lane]   = w;
        }
    } else {
        taken = ~0ull;
        float m = -1.0e30f;
#pragma unroll
        for (int n = 0; n < NM; ++n) m = s[n] > m ? s[n] : m;
        mmax = m;
#pragma unroll
        for (int n = 0; n < NM; ++n) Z += expf(s[n] - mmax);
    }

    // ---- attention weights (fp32, IEEE divide to match np exp/sum)
    {
        float* aout = out_attn + (size_t)row * NM;
#pragma unroll
        for (int n = 0; n < NM; ++n) {
            const bool t = ((taken >> n) & 1ull) != 0ull;
            const float w = t ? expf(s[n] - mmax) / Z : 0.f;
            aout[n] = w;
        }
    }

    // ---- retrieved = sum_sel (w~/Z) * mem[idx]
    {
        float* rout = out_ret + (size_t)row * DD;
        if (k < NM) {
            const int kk = k < 16 ? k : 16;
            for (int dc = 0; dc < 4; ++dc) {
                float r[64];
#pragma unroll
                for (int d = 0; d < 64; ++d) r[d] = 0.f;
                for (int i = 0; i < kk; ++i) {
                    const int idx = sel_idx[i * 64 + lane];
                    const float w = sel_w[i * 64 + lane] / Z;
                    const float* mrow = mem + idx * DD + dc * 64;
#pragma unroll
                    for (int d = 0; d < 64; ++d)
                        r[d] = fmaf(w, mrow[d], r[d]);
                }
#pragma unroll
                for (int d = 0; d < 64; ++d)
                    rout[dc * 64 + d] = r[d];
            }
        } else {
            for (int dc = 0; dc < 4; ++dc) {
                float r[64];
#pragma unroll
                for (int d = 0; d < 64; ++d) r[d] = 0.f;
#pragma unroll
                for (int n = 0; n < NM; ++n) {
                    const float w = expf(s[n] - mmax) / Z;
                    const float* mrow = mem + n * DD + dc * 64;
#pragma unroll
                    for (int d = 0; d < 64; ++d)
                        r[d] = fmaf(w, mrow[d], r[d]);
                }
#pragma unroll
                for (int d = 0; d < 64; ++d)
                    rout[dc * 64 + d] = r[d];
            }
        }
    }
}

// ---------------------------------------------------------------------------
extern "C" void kernel_launch(void* const* d_in, const int* in_sizes, int n_in,
                              void* d_out, int out_size, void* d_ws, size_t ws_size,
                              hipStream_t stream) {
    const float* query      = (const float*)d_in[0];
    const float* memory     = (const float*)d_in[1];
    const float* importance = (const float*)d_in[2];
    const float* age        = (const float*)d_in[3];
    const float* Wq         = (const float*)d_in[4];
    const float* Wk         = (const float*)d_in[5];
    const int*   topk       = (const int*)d_in[6];

    const int M = in_sizes[0] / DD;   // B*S = 131072

    float* kT   = (float*)d_ws;                      // [DD][NM]
    float* bias = kT + (size_t)DD * NM;              // [NM]

    hipLaunchKernelGGL(prep_kT, dim3(NM), dim3(DD), 0, stream,
                       memory, Wk, importance, age, kT, bias);

    float* out_ret  = (float*)d_out;
    float* out_attn = out_ret + (size_t)M * DD;

    hipLaunchKernelGGL(mb_main, dim3((M + 63) / 64), dim3(64), 0, stream,
                       query, memory, Wq, kT, bias, topk, out_ret, out_attn, M);
}

// Round 5
// 911.262 us; speedup vs baseline: 3.1868x; 3.1868x over previous
//
#include <hip/hip_runtime.h>
#include <hip/hip_bf16.h>

#define DD 256      // feature dim
#define NM 64       // memory slots
#define RPB 32      // rows per block (main kernel)
#define NTHR 256

typedef unsigned long long u64;

// ---------------------------------------------------------------------------
// prep: kT4[og][n][4] with kT4[(o>>2)*(NM*4) + n*4 + (o&3)] = k[n][o]
//       k[n][o] = sum_d mem[n][d]*Wk[o][d]  (fp32, d-ascending single-acc FMA)
//       bias[n] = fl32(max(log(imp*0.99^age), -10))
// ---------------------------------------------------------------------------
__global__ __launch_bounds__(256) void prep_kT(
    const float* __restrict__ mem,   // [NM][DD]
    const float* __restrict__ Wk,    // [DD][DD]
    const float* __restrict__ imp,   // [NM]
    const float* __restrict__ age,   // [NM]
    float* __restrict__ kT4,         // out [DD/4][NM][4]
    float* __restrict__ bias)        // out [NM]
{
    const int n = blockIdx.x;   // memory slot
    const int o = threadIdx.x;  // output feature
    const float* mrow = mem + n * DD;
    const float* wrow = Wk + o * DD;
    float acc = 0.f;
    for (int d = 0; d < DD; ++d)
        acc = fmaf(mrow[d], wrow[d], acc);
    kT4[(o >> 2) * (NM * 4) + n * 4 + (o & 3)] = acc;

    if (o == 0) {
        double eff = (double)imp[n] * pow(0.99, (double)age[n]);
        float b = (float)log(eff);
        if (!(b >= -10.0f)) b = -10.0f;   // catches -inf/NaN too
        bias[n] = b;
    }
}

// ---------------------------------------------------------------------------
// fused main: per block 32 query rows.
//  A: q = query @ Wq^T   (chains: d-ascending, single acc per (row,o))
//  B: s = q @ kT         (chains: o-ascending)
//  2: per-row top-k (strict >, lowest-index ties), softmax pieces
//  3: attn + retrieved stores (PV chain: rank-ascending, w = sel_w[i]/Z)
// ---------------------------------------------------------------------------
__global__ __launch_bounds__(NTHR) void mb_fused(
    const float* __restrict__ query,   // [M][DD]
    const float* __restrict__ mem,     // [NM][DD]
    const float* __restrict__ Wq,      // [DD][DD]
    const float* __restrict__ kT4,     // [DD/4][NM][4]
    const float* __restrict__ bias,    // [NM]
    const int* __restrict__ topk_p,
    float* __restrict__ out_ret,       // [M][DD]
    float* __restrict__ out_attn,      // [M][NM]
    int M)
{
    __shared__ float q_lds[RPB * DD];        // 32 KB, [row][o]
    __shared__ float s_lds[RPB][68];         // scores -> then attn weights
    __shared__ int   sel_i[RPB][16];
    __shared__ float sel_w[RPB][16];         // raw exp(m-mmax), then /Z

    const int t = threadIdx.x;
    const int l = t & 63;
    const int w = __builtin_amdgcn_readfirstlane((int)(t >> 6));  // wave id
    const int row0 = blockIdx.x * RPB;
    const int k = *topk_p;

    // ================= Phase A: q-GEMM =================
    // wave w owns rows row0 + 8w + rr (rr=0..7); lane owns o = 4l..4l+3
    {
        const int obase = l * 4;
        const float* wqb = Wq + (size_t)obase * DD;

        const float* qb[8];
#pragma unroll
        for (int rr = 0; rr < 8; ++rr) {
            int r = row0 + w * 8 + rr;
            if (r > M - 1) r = M - 1;
            qb[rr] = query + (size_t)r * DD;   // wave-uniform
        }

        float a0[8], a1[8], a2[8], a3[8];
#pragma unroll
        for (int rr = 0; rr < 8; ++rr) { a0[rr] = 0.f; a1[rr] = 0.f; a2[rr] = 0.f; a3[rr] = 0.f; }

        for (int d0 = 0; d0 < DD; d0 += 4) {
            const float4 b0 = *reinterpret_cast<const float4*>(wqb + d0);
            const float4 b1 = *reinterpret_cast<const float4*>(wqb + DD + d0);
            const float4 b2 = *reinterpret_cast<const float4*>(wqb + 2 * DD + d0);
            const float4 b3 = *reinterpret_cast<const float4*>(wqb + 3 * DD + d0);
#pragma unroll
            for (int rr = 0; rr < 8; ++rr) {
                const float4 sq = *reinterpret_cast<const float4*>(qb[rr] + d0);
                float v0 = a0[rr], v1 = a1[rr], v2 = a2[rr], v3 = a3[rr];
                v0 = fmaf(sq.x, b0.x, v0); v0 = fmaf(sq.y, b0.y, v0);
                v0 = fmaf(sq.z, b0.z, v0); v0 = fmaf(sq.w, b0.w, v0);
                v1 = fmaf(sq.x, b1.x, v1); v1 = fmaf(sq.y, b1.y, v1);
                v1 = fmaf(sq.z, b1.z, v1); v1 = fmaf(sq.w, b1.w, v1);
                v2 = fmaf(sq.x, b2.x, v2); v2 = fmaf(sq.y, b2.y, v2);
                v2 = fmaf(sq.z, b2.z, v2); v2 = fmaf(sq.w, b2.w, v2);
                v3 = fmaf(sq.x, b3.x, v3); v3 = fmaf(sq.y, b3.y, v3);
                v3 = fmaf(sq.z, b3.z, v3); v3 = fmaf(sq.w, b3.w, v3);
                a0[rr] = v0; a1[rr] = v1; a2[rr] = v2; a3[rr] = v3;
            }
        }
#pragma unroll
        for (int rr = 0; rr < 8; ++rr) {
            float4 v; v.x = a0[rr]; v.y = a1[rr]; v.z = a2[rr]; v.w = a3[rr];
            *reinterpret_cast<float4*>(&q_lds[(w * 8 + rr) * DD + obase]) = v;
        }
    }
    __syncthreads();

    // ================= Phase B: scores =================
    // lane = n (0..63), wave w handles rows 8w..8w+7
    {
        const int n = l;
        float sc[8];
#pragma unroll
        for (int rr = 0; rr < 8; ++rr) sc[rr] = 0.f;

        for (int og = 0; og < DD / 4; ++og) {
            const float4 kt = *reinterpret_cast<const float4*>(kT4 + (size_t)og * (NM * 4) + n * 4);
#pragma unroll
            for (int rr = 0; rr < 8; ++rr) {
                const float4 q4 = *reinterpret_cast<const float4*>(&q_lds[(w * 8 + rr) * DD + og * 4]);
                float v = sc[rr];
                v = fmaf(q4.x, kt.x, v);
                v = fmaf(q4.y, kt.y, v);
                v = fmaf(q4.z, kt.z, v);
                v = fmaf(q4.w, kt.w, v);
                sc[rr] = v;
            }
        }
        const float bn = bias[n];
#pragma unroll
        for (int rr = 0; rr < 8; ++rr)
            s_lds[w * 8 + rr][n] = sc[rr] * 0.0625f + bn;   // /16 exact, then add
    }
    __syncthreads();

    // ================= Phase 2: per-row top-k =================
    if ((t & 7) == 0) {
        const int r = t >> 3;           // 0..31
        float sv[NM];
#pragma unroll
        for (int n = 0; n < NM; ++n) sv[n] = s_lds[r][n];

        if (k < NM) {
            const int kk = k < 16 ? k : 16;   // dataset: k = 8
            u64 taken = 0ull;
            float mmax = 0.f, Z = 0.f;
            for (int i = 0; i < kk; ++i) {
                float m = -1.0e30f;
                int idx = 0;
#pragma unroll
                for (int n = 0; n < NM; ++n) {
                    const bool avail  = ((taken >> n) & 1ull) == 0ull;
                    const bool better = avail && (sv[n] > m);  // strict >: lowest idx ties
                    m   = better ? sv[n] : m;
                    idx = better ? n : idx;
                }
                taken |= (1ull << idx);
                if (i == 0) mmax = m;
                const float wv = expf(m - mmax);
                Z += wv;
                sel_i[r][i] = idx;
                sel_w[r][i] = wv;       // raw, divided below once Z final
            }
            // w-row: zeros except selected = sel_w/Z (== expf(s-mmax)/Z)
#pragma unroll
            for (int n = 0; n < NM; ++n) s_lds[r][n] = 0.f;
            for (int i = 0; i < kk; ++i) {
                const float wz = sel_w[r][i] / Z;
                sel_w[r][i] = wz;
                s_lds[r][sel_i[r][i]] = wz;
            }
        } else {
            // full-softmax fallback (top_k >= N)
            float m = -1.0e30f;
#pragma unroll
            for (int n = 0; n < NM; ++n) m = sv[n] > m ? sv[n] : m;
            float Z = 0.f;
#pragma unroll
            for (int n = 0; n < NM; ++n) Z += expf(sv[n] - m);
#pragma unroll
            for (int n = 0; n < NM; ++n) s_lds[r][n] = expf(sv[n] - m) / Z;
        }
    }
    __syncthreads();

    // ================= Phase 3a: attn stores (coalesced) =================
#pragma unroll
    for (int it = 0; it < (RPB * NM) / NTHR; ++it) {   // 8 iters
        const int idx  = it * NTHR + t;
        const int r    = idx >> 6, n = idx & 63;
        const int grow = row0 + r;
        if (grow < M) out_attn[(size_t)grow * NM + n] = s_lds[r][n];
    }

    // ================= Phase 3b: retrieved (PV) =================
    // lanes = d (NTHR == DD); one row per iteration
    {
        const int kk = k < 16 ? k : 16;
        for (int r = 0; r < RPB; ++r) {
            const int grow = row0 + r;
            if (grow >= M) break;
            float a = 0.f;
            if (k < NM) {
                for (int i = 0; i < kk; ++i) {
                    const int   mi = sel_i[r][i];
                    const float wz = sel_w[r][i];
                    a = fmaf(wz, mem[(size_t)mi * DD + t], a);   // rank-ascending chain
                }
            } else {
                for (int n = 0; n < NM; ++n)
                    a = fmaf(s_lds[r][n], mem[(size_t)n * DD + t], a);  // n-ascending
            }
            out_ret[(size_t)grow * DD + t] = a;
        }
    }
}

// ---------------------------------------------------------------------------
extern "C" void kernel_launch(void* const* d_in, const int* in_sizes, int n_in,
                              void* d_out, int out_size, void* d_ws, size_t ws_size,
                              hipStream_t stream) {
    const float* query      = (const float*)d_in[0];
    const float* memory     = (const float*)d_in[1];
    const float* importance = (const float*)d_in[2];
    const float* age        = (const float*)d_in[3];
    const float* Wq         = (const float*)d_in[4];
    const float* Wk         = (const float*)d_in[5];
    const int*   topk       = (const int*)d_in[6];

    const int M = in_sizes[0] / DD;   // B*S = 131072

    float* kT4  = (float*)d_ws;                      // [DD/4][NM][4] = 64 KB
    float* bias = kT4 + (size_t)DD * NM;             // [NM]

    hipLaunchKernelGGL(prep_kT, dim3(NM), dim3(DD), 0, stream,
                       memory, Wk, importance, age, kT4, bias);

    float* out_ret  = (float*)d_out;
    float* out_attn = out_ret + (size_t)M * DD;

    hipLaunchKernelGGL(mb_fused, dim3((M + RPB - 1) / RPB), dim3(NTHR), 0, stream,
                       query, memory, Wq, kT4, bias, topk, out_ret, out_attn, M);
}

// Round 6
// 665.434 us; speedup vs baseline: 4.3641x; 1.3694x over previous
//
#include <hip/hip_runtime.h>
#include <hip/hip_bf16.h>

#define DD 256      // feature dim
#define NM 64       // memory slots
#define RPB 16      // rows per block (main kernel)
#define NTHR 256    // 4 waves; wave handles 4 rows

typedef unsigned long long u64;

// ---------------------------------------------------------------------------
// prep: kT4[og][n][4] with kT4[(o>>2)*(NM*4) + n*4 + (o&3)] = k[n][o]
//       k[n][o] = sum_d mem[n][d]*Wk[o][d]  (fp32, d-ascending single-acc FMA)
//       bias[n] = fl32(max(log(imp*0.99^age), -10))
// ---------------------------------------------------------------------------
__global__ __launch_bounds__(256) void prep_kT(
    const float* __restrict__ mem,   // [NM][DD]
    const float* __restrict__ Wk,    // [DD][DD]
    const float* __restrict__ imp,   // [NM]
    const float* __restrict__ age,   // [NM]
    float* __restrict__ kT4,         // out [DD/4][NM][4]
    float* __restrict__ bias)        // out [NM]
{
    const int n = blockIdx.x;   // memory slot
    const int o = threadIdx.x;  // output feature
    const float* mrow = mem + n * DD;
    const float* wrow = Wk + o * DD;
    float acc = 0.f;
    for (int d = 0; d < DD; ++d)
        acc = fmaf(mrow[d], wrow[d], acc);
    kT4[(o >> 2) * (NM * 4) + n * 4 + (o & 3)] = acc;

    if (o == 0) {
        double eff = (double)imp[n] * pow(0.99, (double)age[n]);
        float b = (float)log(eff);
        if (!(b >= -10.0f)) b = -10.0f;   // catches -inf/NaN too
        bias[n] = b;
    }
}

// ---------------------------------------------------------------------------
// prep_wqt: wqt[d][o] = Wq[o][d]  (pure transpose copy -> coalesced Phase A)
// ---------------------------------------------------------------------------
__global__ __launch_bounds__(256) void prep_wqt(
    const float* __restrict__ Wq,    // [DD][DD]
    float* __restrict__ wqt)         // out [DD][DD]
{
    const int d = blockIdx.x;
    const int o = threadIdx.x;
    wqt[d * DD + o] = Wq[o * DD + d];
}

// ---------------------------------------------------------------------------
// fused main: per block 16 query rows, 4 waves x 4 rows.
//  A: q = query @ Wq^T  (chain per (row,o): d-ascending single-acc fmaf;
//     wqt read coalesced: lane l holds o=4l..4l+3)
//  B: s = q @ kT        (chain o-ascending), /16, +bias
//  2: per-row top-k (strict >, lowest-index ties), softmax pieces
//  3: attn + retrieved stores (PV chain: rank-ascending, w = sel_w[i]/Z)
// ---------------------------------------------------------------------------
__global__ __launch_bounds__(NTHR, 6) void mb_fused(
    const float* __restrict__ query,   // [M][DD]
    const float* __restrict__ mem,     // [NM][DD]
    const float4* __restrict__ wqt4,   // [DD][NM] float4 view: wqt4[d*64+l] = WqT[d][4l..4l+3]
    const float4* __restrict__ kT44,   // [DD/4][NM] float4 view
    const float* __restrict__ bias,    // [NM]
    const int* __restrict__ topk_p,
    float* __restrict__ out_ret,       // [M][DD]
    float* __restrict__ out_attn,      // [M][NM]
    int M)
{
    __shared__ float q_lds[RPB * DD];        // 16 KB, [row][o]
    __shared__ float s_lds[RPB][68];         // scores -> then attn weights
    __shared__ int   sel_i[RPB][16];
    __shared__ float sel_w[RPB][16];         // raw exp(m-mmax), then /Z

    const int t = threadIdx.x;
    const int l = t & 63;
    const int w = __builtin_amdgcn_readfirstlane((int)(t >> 6));  // wave id
    const int row0 = blockIdx.x * RPB;
    const int k = *topk_p;

    // ================= Phase A: q-GEMM =================
    // wave w rows: row0 + 4w + rr (rr=0..3); lane l owns o = 4l..4l+3
    {
        const float* qb[4];
#pragma unroll
        for (int rr = 0; rr < 4; ++rr) {
            int r = row0 + w * 4 + rr;
            if (r > M - 1) r = M - 1;
            qb[rr] = query + (size_t)r * DD;   // wave-uniform -> scalar loads
        }

        float a0[4], a1[4], a2[4], a3[4];      // a{c}[rr]: o = 4l + c
#pragma unroll
        for (int rr = 0; rr < 4; ++rr) { a0[rr] = 0.f; a1[rr] = 0.f; a2[rr] = 0.f; a3[rr] = 0.f; }

        for (int d0 = 0; d0 < DD; d0 += 4) {
            const float4 w0 = wqt4[(size_t)(d0 + 0) * NM + l];   // coalesced 1KB/instr
            const float4 w1 = wqt4[(size_t)(d0 + 1) * NM + l];
            const float4 w2 = wqt4[(size_t)(d0 + 2) * NM + l];
            const float4 w3 = wqt4[(size_t)(d0 + 3) * NM + l];
#pragma unroll
            for (int rr = 0; rr < 4; ++rr) {
                const float4 qq = *reinterpret_cast<const float4*>(qb[rr] + d0); // uniform
                float v0 = a0[rr], v1 = a1[rr], v2 = a2[rr], v3 = a3[rr];
                // d-ascending per chain: d0 (w0), d0+1 (w1), d0+2 (w2), d0+3 (w3)
                v0 = fmaf(qq.x, w0.x, v0); v0 = fmaf(qq.y, w1.x, v0);
                v0 = fmaf(qq.z, w2.x, v0); v0 = fmaf(qq.w, w3.x, v0);
                v1 = fmaf(qq.x, w0.y, v1); v1 = fmaf(qq.y, w1.y, v1);
                v1 = fmaf(qq.z, w2.y, v1); v1 = fmaf(qq.w, w3.y, v1);
                v2 = fmaf(qq.x, w0.z, v2); v2 = fmaf(qq.y, w1.z, v2);
                v2 = fmaf(qq.z, w2.z, v2); v2 = fmaf(qq.w, w3.z, v2);
                v3 = fmaf(qq.x, w0.w, v3); v3 = fmaf(qq.y, w1.w, v3);
                v3 = fmaf(qq.z, w2.w, v3); v3 = fmaf(qq.w, w3.w, v3);
                a0[rr] = v0; a1[rr] = v1; a2[rr] = v2; a3[rr] = v3;
            }
        }
#pragma unroll
        for (int rr = 0; rr < 4; ++rr) {
            float4 v; v.x = a0[rr]; v.y = a1[rr]; v.z = a2[rr]; v.w = a3[rr];
            *reinterpret_cast<float4*>(&q_lds[(w * 4 + rr) * DD + 4 * l]) = v;
        }
    }
    __syncthreads();

    // ================= Phase B: scores =================
    // lane = n (0..63), wave w rows 4w..4w+3
    {
        const int n = l;
        float sc[4] = {0.f, 0.f, 0.f, 0.f};
        const float4* qld = reinterpret_cast<const float4*>(q_lds);

        for (int og = 0; og < DD / 4; ++og) {
            const float4 kt = kT44[og * NM + n];          // coalesced, L2-hot
#pragma unroll
            for (int rr = 0; rr < 4; ++rr) {
                const float4 q4 = qld[(w * 4 + rr) * (DD / 4) + og];  // broadcast
                float v = sc[rr];
                v = fmaf(q4.x, kt.x, v);
                v = fmaf(q4.y, kt.y, v);
                v = fmaf(q4.z, kt.z, v);
                v = fmaf(q4.w, kt.w, v);
                sc[rr] = v;
            }
        }
        const float bn = bias[n];
#pragma unroll
        for (int rr = 0; rr < 4; ++rr)
            s_lds[w * 4 + rr][n] = sc[rr] * 0.0625f + bn;   // same expr as passing version
    }
    __syncthreads();

    // ================= Phase 2: per-row top-k =================
    if ((t & 15) == 0) {
        const int r = t >> 4;           // 0..15
        float sv[NM];
#pragma unroll
        for (int n = 0; n < NM; ++n) sv[n] = s_lds[r][n];

        if (k < NM) {
            const int kk = k < 16 ? k : 16;   // dataset: k = 8
            u64 taken = 0ull;
            float mmax = 0.f, Z = 0.f;
            for (int i = 0; i < kk; ++i) {
                float m = -1.0e30f;
                int idx = 0;
#pragma unroll
                for (int n = 0; n < NM; ++n) {
                    const bool avail  = ((taken >> n) & 1ull) == 0ull;
                    const bool better = avail && (sv[n] > m);  // strict >: lowest idx ties
                    m   = better ? sv[n] : m;
                    idx = better ? n : idx;
                }
                taken |= (1ull << idx);
                if (i == 0) mmax = m;
                const float wv = expf(m - mmax);
                Z += wv;
                sel_i[r][i] = idx;
                sel_w[r][i] = wv;       // raw; divided once Z final
            }
#pragma unroll
            for (int n = 0; n < NM; ++n) s_lds[r][n] = 0.f;
            for (int i = 0; i < kk; ++i) {
                const float wz = sel_w[r][i] / Z;
                sel_w[r][i] = wz;
                s_lds[r][sel_i[r][i]] = wz;
            }
        } else {
            // full-softmax fallback (top_k >= N)
            float m = -1.0e30f;
#pragma unroll
            for (int n = 0; n < NM; ++n) m = sv[n] > m ? sv[n] : m;
            float Z = 0.f;
#pragma unroll
            for (int n = 0; n < NM; ++n) Z += expf(sv[n] - m);
#pragma unroll
            for (int n = 0; n < NM; ++n) s_lds[r][n] = expf(sv[n] - m) / Z;
        }
    }
    __syncthreads();

    // ================= Phase 3a: attn stores (coalesced) =================
#pragma unroll
    for (int it = 0; it < (RPB * NM) / NTHR; ++it) {   // 4 iters
        const int idx  = it * NTHR + t;
        const int r    = idx >> 6, n = idx & 63;
        const int grow = row0 + r;
        if (grow < M) out_attn[(size_t)grow * NM + n] = s_lds[r][n];
    }

    // ================= Phase 3b: retrieved (PV) =================
    // lanes = d (NTHR == DD); one row per iteration
    {
        const int kk = k < 16 ? k : 16;
        for (int r = 0; r < RPB; ++r) {
            const int grow = row0 + r;
            if (grow >= M) break;
            float a = 0.f;
            if (k < NM) {
                for (int i = 0; i < kk; ++i) {
                    const int   mi = sel_i[r][i];
                    const float wz = sel_w[r][i];
                    a = fmaf(wz, mem[(size_t)mi * DD + t], a);   // rank-ascending chain
                }
            } else {
                for (int n = 0; n < NM; ++n)
                    a = fmaf(s_lds[r][n], mem[(size_t)n * DD + t], a);  // n-ascending
            }
            out_ret[(size_t)grow * DD + t] = a;
        }
    }
}

// ---------------------------------------------------------------------------
extern "C" void kernel_launch(void* const* d_in, const int* in_sizes, int n_in,
                              void* d_out, int out_size, void* d_ws, size_t ws_size,
                              hipStream_t stream) {
    const float* query      = (const float*)d_in[0];
    const float* memory     = (const float*)d_in[1];
    const float* importance = (const float*)d_in[2];
    const float* age        = (const float*)d_in[3];
    const float* Wq         = (const float*)d_in[4];
    const float* Wk         = (const float*)d_in[5];
    const int*   topk       = (const int*)d_in[6];

    const int M = in_sizes[0] / DD;   // B*S = 131072

    float* kT4  = (float*)d_ws;                      // [DD/4][NM][4] = 64 KB
    float* bias = kT4 + (size_t)DD * NM;             // [NM]
    float* wqt  = bias + 64;                         // [DD][DD] = 256 KB (16B-aligned)

    hipLaunchKernelGGL(prep_kT, dim3(NM), dim3(DD), 0, stream,
                       memory, Wk, importance, age, kT4, bias);
    hipLaunchKernelGGL(prep_wqt, dim3(DD), dim3(DD), 0, stream,
                       Wq, wqt);

    float* out_ret  = (float*)d_out;
    float* out_attn = out_ret + (size_t)M * DD;

    hipLaunchKernelGGL(mb_fused, dim3((M + RPB - 1) / RPB), dim3(NTHR), 0, stream,
                       query, memory,
                       (const float4*)wqt, (const float4*)kT4,
                       bias, topk, out_ret, out_attn, M);
}

// Round 7
// 649.653 us; speedup vs baseline: 4.4701x; 1.0243x over previous
//
#include <hip/hip_runtime.h>
#include <hip/hip_bf16.h>

#define DD 256      // feature dim
#define NM 64       // memory slots
#define RPB 64      // rows per block (main kernel)
#define NTHR 512    // 8 waves

typedef unsigned long long u64;

// ---------------------------------------------------------------------------
// prep_tr: wt[d][o] = W[o][d] for Wq and Wk (read-coalesced, scatter-write)
// ---------------------------------------------------------------------------
__global__ __launch_bounds__(256) void prep_tr(
    const float* __restrict__ Wq,    // [DD][DD]
    const float* __restrict__ Wk,    // [DD][DD]
    float* __restrict__ wqt,         // out [DD][DD]
    float* __restrict__ wkt)         // out [DD][DD]
{
    const int o = blockIdx.x;    // source row
    const int d = threadIdx.x;   // source col (coalesced read)
    if (blockIdx.y == 0) wqt[d * DD + o] = Wq[o * DD + d];
    else                 wkt[d * DD + o] = Wk[o * DD + d];
}

// ---------------------------------------------------------------------------
// prep_kT: kT4[(o>>2)*(NM*4) + n*4 + (o&3)] = k[n][o]
//          k[n][o] = sum_d mem[n][d]*Wk[o][d]  (fp32, d-ascending single-acc)
//          bias[n] = fl32(max(log(imp*0.99^age), -10))
// ---------------------------------------------------------------------------
__global__ __launch_bounds__(256) void prep_kT(
    const float* __restrict__ mem,   // [NM][DD]
    const float* __restrict__ wkt,   // [DD][DD]  (WkT: wkt[d][o])
    const float* __restrict__ imp,   // [NM]
    const float* __restrict__ age,   // [NM]
    float* __restrict__ kT4,         // out [DD/4][NM][4]
    float* __restrict__ bias)        // out [NM]
{
    const int n = blockIdx.x;   // memory slot
    const int o = threadIdx.x;  // output feature
    const float* mrow = mem + n * DD;     // uniform
    float acc = 0.f;
    for (int d = 0; d < DD; ++d)
        acc = fmaf(mrow[d], wkt[d * DD + o], acc);   // coalesced in o
    kT4[(o >> 2) * (NM * 4) + n * 4 + (o & 3)] = acc;

    if (o == 0) {
        double eff = (double)imp[n] * pow(0.99, (double)age[n]);
        float b = (float)log(eff);
        if (!(b >= -10.0f)) b = -10.0f;   // catches -inf/NaN too
        bias[n] = b;
    }
}

// ---------------------------------------------------------------------------
// fused main: 64 rows/block, 512 threads (8 waves).
//  A: q = query @ Wq^T   (wave w: rows 8w..8w+7; lane l: o=4l..4l+3;
//     chain per (row,o): d-ascending single-acc fmaf — bit-identical to R6)
//  B: s = q @ kT         (lane = row, wave = 8-n set; kT via uniform s_load;
//     chain per (row,n): o-ascending — bit-identical to R6)
//  2: per-row top-k (wave 0, lane = row)
//  3: attn + retrieved stores (PV chain rank-ascending — bit-identical)
// q_lds swizzle: row lr, o-slot p stored at p^lr  -> conflict-free both ways.
// ---------------------------------------------------------------------------
__global__ __launch_bounds__(NTHR, 1) void mb_fused(
    const float* __restrict__ query,   // [M][DD]
    const float* __restrict__ mem,     // [NM][DD]
    const float4* __restrict__ wqt4,   // [DD][NM]: wqt4[d*64+l] = WqT[d][4l..4l+3]
    const float4* __restrict__ kT44,   // [DD/4][NM]: kT44[og*64+n] = k[n][4og..4og+3]
    const float* __restrict__ bias,    // [NM]
    const int* __restrict__ topk_p,
    float* __restrict__ out_ret,       // [M][DD]
    float* __restrict__ out_attn,      // [M][NM]
    int M)
{
    __shared__ float q_lds[RPB * DD];        // 64 KB, swizzled
    __shared__ float s_lds[RPB][65];         // pad 65: conflict-free row gather
    __shared__ int   sel_i[RPB][16];
    __shared__ float sel_w[RPB][16];

    const int t = threadIdx.x;
    const int l = t & 63;
    const int w = __builtin_amdgcn_readfirstlane((int)(t >> 6));  // 0..7
    const int row0 = blockIdx.x * RPB;
    const int k = *topk_p;

    // ================= Phase A: q-GEMM =================
    {
        const float* qb[8];
#pragma unroll
        for (int rr = 0; rr < 8; ++rr) {
            int r = row0 + w * 8 + rr;
            if (r > M - 1) r = M - 1;
            qb[rr] = query + (size_t)r * DD;   // wave-uniform
        }

        float a0[8], a1[8], a2[8], a3[8];      // a{c}[rr]: o = 4l + c
#pragma unroll
        for (int rr = 0; rr < 8; ++rr) { a0[rr] = 0.f; a1[rr] = 0.f; a2[rr] = 0.f; a3[rr] = 0.f; }

        for (int d0 = 0; d0 < DD; d0 += 4) {
            const float4 w0 = wqt4[(d0 + 0) * NM + l];   // coalesced 1KB/instr
            const float4 w1 = wqt4[(d0 + 1) * NM + l];
            const float4 w2 = wqt4[(d0 + 2) * NM + l];
            const float4 w3 = wqt4[(d0 + 3) * NM + l];
#pragma unroll
            for (int rr = 0; rr < 8; ++rr) {
                const float4 qq = *reinterpret_cast<const float4*>(qb[rr] + d0); // uniform
                float v0 = a0[rr], v1 = a1[rr], v2 = a2[rr], v3 = a3[rr];
                // d-ascending per chain (identical to R6)
                v0 = fmaf(qq.x, w0.x, v0); v0 = fmaf(qq.y, w1.x, v0);
                v0 = fmaf(qq.z, w2.x, v0); v0 = fmaf(qq.w, w3.x, v0);
                v1 = fmaf(qq.x, w0.y, v1); v1 = fmaf(qq.y, w1.y, v1);
                v1 = fmaf(qq.z, w2.y, v1); v1 = fmaf(qq.w, w3.y, v1);
                v2 = fmaf(qq.x, w0.z, v2); v2 = fmaf(qq.y, w1.z, v2);
                v2 = fmaf(qq.z, w2.z, v2); v2 = fmaf(qq.w, w3.z, v2);
                v3 = fmaf(qq.x, w0.w, v3); v3 = fmaf(qq.y, w1.w, v3);
                v3 = fmaf(qq.z, w2.w, v3); v3 = fmaf(qq.w, w3.w, v3);
                a0[rr] = v0; a1[rr] = v1; a2[rr] = v2; a3[rr] = v3;
            }
        }
#pragma unroll
        for (int rr = 0; rr < 8; ++rr) {
            const int lr = w * 8 + rr;
            float4 v; v.x = a0[rr]; v.y = a1[rr]; v.z = a2[rr]; v.w = a3[rr];
            *reinterpret_cast<float4*>(&q_lds[lr * DD + (((l ^ lr) & 63) << 2)]) = v;
        }
    }
    __syncthreads();

    // ================= Phase B: scores =================
    // lane = row l; wave w owns n in [8w, 8w+8)
    {
        const int nb = w * 8;
        float sc[8];
#pragma unroll
        for (int j = 0; j < 8; ++j) sc[j] = 0.f;

        for (int og = 0; og < DD / 4; ++og) {
            const float4 q4 = *reinterpret_cast<const float4*>(
                &q_lds[l * DD + (((og ^ l) & 63) << 2)]);     // 1 read / 64 rows
            const float4* ktp = kT44 + og * NM + nb;          // wave-uniform -> s_load
#pragma unroll
            for (int j = 0; j < 8; ++j) {
                const float4 kt = ktp[j];
                float v = sc[j];
                v = fmaf(q4.x, kt.x, v);
                v = fmaf(q4.y, kt.y, v);
                v = fmaf(q4.z, kt.z, v);
                v = fmaf(q4.w, kt.w, v);
                sc[j] = v;
            }
        }
#pragma unroll
        for (int j = 0; j < 8; ++j)
            s_lds[l][nb + j] = sc[j] * 0.0625f + bias[nb + j];  // same expr as R6
    }
    __syncthreads();

    // ================= Phase 2: per-row top-k (wave 0, lane = row) =================
    if (t < RPB) {
        const int r = t;
        float sv[NM];
#pragma unroll
        for (int n = 0; n < NM; ++n) sv[n] = s_lds[r][n];

        if (k < NM) {
            const int kk = k < 16 ? k : 16;   // dataset: k = 8
            u64 taken = 0ull;
            float mmax = 0.f, Z = 0.f;
            for (int i = 0; i < kk; ++i) {
                float m = -1.0e30f;
                int idx = 0;
#pragma unroll
                for (int n = 0; n < NM; ++n) {
                    const bool avail  = ((taken >> n) & 1ull) == 0ull;
                    const bool better = avail && (sv[n] > m);  // strict >: lowest idx ties
                    m   = better ? sv[n] : m;
                    idx = better ? n : idx;
                }
                taken |= (1ull << idx);
                if (i == 0) mmax = m;
                const float wv = expf(m - mmax);
                Z += wv;
                sel_i[r][i] = idx;
                sel_w[r][i] = wv;       // raw; divided once Z final
            }
#pragma unroll
            for (int n = 0; n < NM; ++n) s_lds[r][n] = 0.f;
            for (int i = 0; i < kk; ++i) {
                const float wz = sel_w[r][i] / Z;
                sel_w[r][i] = wz;
                s_lds[r][sel_i[r][i]] = wz;
            }
        } else {
            // full-softmax fallback (top_k >= N)
            float m = -1.0e30f;
#pragma unroll
            for (int n = 0; n < NM; ++n) m = sv[n] > m ? sv[n] : m;
            float Z = 0.f;
#pragma unroll
            for (int n = 0; n < NM; ++n) Z += expf(sv[n] - m);
#pragma unroll
            for (int n = 0; n < NM; ++n) s_lds[r][n] = expf(sv[n] - m) / Z;
        }
    }
    __syncthreads();

    // ================= Phase 3a: attn stores (coalesced) =================
#pragma unroll
    for (int it = 0; it < (RPB * NM) / NTHR; ++it) {   // 8 iters
        const int idx  = it * NTHR + t;
        const int r    = idx >> 6, n = idx & 63;
        const int grow = row0 + r;
        if (grow < M) out_attn[(size_t)grow * NM + n] = s_lds[r][n];
    }

    // ================= Phase 3b: retrieved (PV) =================
    // d = t & 255; half = t >> 8 -> 2 rows per iteration
    {
        const int d  = t & (DD - 1);
        const int rh = t >> 8;               // 0 or 1
        const int kk = k < 16 ? k : 16;
        for (int r0 = 0; r0 < RPB / 2; ++r0) {
            const int r    = r0 * 2 + rh;    // wave-uniform
            const int grow = row0 + r;
            if (grow >= M) continue;
            float a = 0.f;
            if (k < NM) {
                for (int i = 0; i < kk; ++i) {
                    const int   mi = sel_i[r][i];
                    const float wz = sel_w[r][i];
                    a = fmaf(wz, mem[(size_t)mi * DD + d], a);   // rank-ascending chain
                }
            } else {
                for (int n = 0; n < NM; ++n)
                    a = fmaf(s_lds[r][n], mem[(size_t)n * DD + d], a);  // n-ascending
            }
            out_ret[(size_t)grow * DD + d] = a;
        }
    }
}

// ---------------------------------------------------------------------------
extern "C" void kernel_launch(void* const* d_in, const int* in_sizes, int n_in,
                              void* d_out, int out_size, void* d_ws, size_t ws_size,
                              hipStream_t stream) {
    const float* query      = (const float*)d_in[0];
    const float* memory     = (const float*)d_in[1];
    const float* importance = (const float*)d_in[2];
    const float* age        = (const float*)d_in[3];
    const float* Wq         = (const float*)d_in[4];
    const float* Wk         = (const float*)d_in[5];
    const int*   topk       = (const int*)d_in[6];

    const int M = in_sizes[0] / DD;   // B*S = 131072

    float* kT4  = (float*)d_ws;                      // [DD/4][NM][4] = 64 KB
    float* bias = kT4 + (size_t)DD * NM;             // [NM]
    float* wqt  = bias + 64;                         // [DD][DD] = 256 KB (16B aligned)
    float* wkt  = wqt + (size_t)DD * DD;             // [DD][DD] = 256 KB

    hipLaunchKernelGGL(prep_tr, dim3(DD, 2), dim3(DD), 0, stream,
                       Wq, Wk, wqt, wkt);
    hipLaunchKernelGGL(prep_kT, dim3(NM), dim3(DD), 0, stream,
                       memory, wkt, importance, age, kT4, bias);

    float* out_ret  = (float*)d_out;
    float* out_attn = out_ret + (size_t)M * DD;

    hipLaunchKernelGGL(mb_fused, dim3((M + RPB - 1) / RPB), dim3(NTHR), 0, stream,
                       query, memory,
                       (const float4*)wqt, (const float4*)kT4,
                       bias, topk, out_ret, out_attn, M);
}